// Round 16
// baseline (158.761 us; speedup 1.0000x reference)
//
#include <hip/hip_runtime.h>
#include <math.h>

// SoftKConv, round 29 (= r28 resubmitted; r28 bench died on GPU acquisition
// timeout — no data). DIFFERENTIAL DIAGNOSTIC.
// r27 post-mortem: persistent gemm NULL (146.8->145.9). Falsified gemm
// theories: wave-starvation (r19), launch count (r20), txn-bound (r21, only
// -10), per-block cost (r27). Accounting: gemm+gap ~= 75us with gemm<63.4
// (absent from top-5) and NO lower bound. Two irreconcilable hypotheses:
//   H1 gemm~60 (slow, unknown cause), gap~15
//   H2 gemm~12 (roofline), gap~60 (CP drain + cross-XCD L2 writeback at the
//      dependent-kernel boundary — the same mechanism that nuked r18's coop)
// r28/r29: launch gemm TWICE (idempotent — second writes identical hq
// bytes). delta(dur_us) vs r27's 145.9 = exactly one (gemm + boundary-gap).
// H1 => dur >= ~205. H2 => dur <= ~172. softk/absmax unchanged either way.
// Kernels themselves = r27 exactly.

typedef __attribute__((ext_vector_type(2)))  _Float16 half2v;
typedef __attribute__((ext_vector_type(4)))  _Float16 half4v;
typedef __attribute__((ext_vector_type(8)))  _Float16 half8;
typedef __attribute__((ext_vector_type(16))) float    f32x16;

#define NK   32
#define DIM  128
// softk LDS row stride 272 B (64 dwords used + 4 pad); rotation 16*(k&3) dwords.
#define ROWB 272
// waves (independent node streams) per softk workgroup
#define WPB  3
// persistent gemm grid
#define GEMM_BLOCKS 512

// ---------------- Kernel 1: h = feat @ W -> f16, persistent MFMA -----------
__global__ __launch_bounds__(256) void gemm128(
    const float* __restrict__ A, const float* __restrict__ W,
    _Float16* __restrict__ Hq, int n)
{
    // 32 rows x 132 floats (528 B stride: 16B-aligned, pad kills pow2 stride)
    __shared__ __align__(16) char smem[32 * 528];          // 16896 B

    const int tid  = threadIdx.x;
    const int lane = tid & 63;
    const int l31  = lane & 31;
    const int hf   = lane >> 5;
    const int t    = tid >> 6;                // col-tile 0..3
    const int col  = l31 + 32 * t;            // output col 0..127

    // staging thread mapping (8 threads/row)
    const int sr = tid >> 3;                  // 0..31
    const int sc = tid & 7;                   // 16B chunk group

    // ---- af fragments from W: ONCE per block (amortized over tiles) ----
    half8 af[8];
#pragma unroll
    for (int s = 0; s < 8; ++s) {
        const float* wp = W + (size_t)(16 * s + 8 * hf) * 128 + col;
#pragma unroll
        for (int e = 0; e < 8; ++e)
            af[s][e] = (_Float16)wp[(size_t)e * 128];
    }

    const int ntiles = (n + 31) >> 5;
    for (int tile = blockIdx.x; tile < ntiles; tile += GEMM_BLOCKS) {
        const int row0 = tile * 32;

        __syncthreads();   // prior iteration's smem readers done

        // ---- stage feat tile: fully coalesced (8 threads/row, 128B runs) --
        {
            int rr = row0 + sr; if (rr >= n) rr = n - 1;
            const float* src = A + (size_t)rr * 128 + 4 * sc;
            char* dst = smem + sr * 528 + 16 * sc;
#pragma unroll
            for (int i = 0; i < 4; ++i) {
                float4 v = *reinterpret_cast<const float4*>(src + 32 * i);
                *reinterpret_cast<float4*>(dst + 128 * i) = v;
            }
        }

        __syncthreads();

        // ---- bf from LDS (row l31, 16B-aligned) + MFMA ----
        f32x16 acc;
#pragma unroll
        for (int i = 0; i < 16; ++i) acc[i] = 0.0f;

        const char* myrow = smem + l31 * 528 + 32 * hf;    // float col 8*hf
#pragma unroll
        for (int s = 0; s < 8; ++s) {
            float4 b0 = *reinterpret_cast<const float4*>(myrow + 64 * s);
            float4 b1 = *reinterpret_cast<const float4*>(myrow + 64 * s + 16);
            half8 bf;
            bf[0] = (_Float16)b0.x; bf[1] = (_Float16)b0.y;
            bf[2] = (_Float16)b0.z; bf[3] = (_Float16)b0.w;
            bf[4] = (_Float16)b1.x; bf[5] = (_Float16)b1.y;
            bf[6] = (_Float16)b1.z; bf[7] = (_Float16)b1.w;
            acc = __builtin_amdgcn_mfma_f32_32x32x16_f16(af[s], bf, acc, 0, 0, 0);
        }

        __syncthreads();                                   // done reading tile

        // ---- stage output f16 tile in LDS (32 rows x 272 B stride) ----
        {
            char* orow = smem + l31 * 272 + 64 * t + 8 * hf;
#pragma unroll
            for (int g = 0; g < 4; ++g) {
                half4v hv;
#pragma unroll
                for (int q = 0; q < 4; ++q) hv[q] = (_Float16)acc[4 * g + q];
                *reinterpret_cast<half4v*>(orow + 16 * g) = hv;
            }
        }

        __syncthreads();

        // ---- coalesced row stores: 8 threads/row, 16B each, 2 iters ----
        {
            const int orow = row0 + sr;
            if (orow < n) {
                const char* srcl = smem + sr * 272 + 16 * sc;
                _Float16*   dst  = Hq + (size_t)orow * 128 + 8 * sc;
#pragma unroll
                for (int i = 0; i < 2; ++i) {
                    half8 v = *reinterpret_cast<const half8*>(srcl + 128 * i);
                    *reinterpret_cast<half8*>(dst + 64 * i) = v;
                }
            }
        }
    }
}

// ---------------- Kernel 2: per-node soft medoid, pipelined ----------------
// 192 threads = 3 independent waves/block, each wave = its own node stream
// with next-node prefetch. No barriers; per-wave LDS slices are disjoint.
__global__ __launch_bounds__(192, 4) void softk(
    const _Float16* __restrict__ hq, const float* __restrict__ bias,
    const float* __restrict__ tkw, const int* __restrict__ idx,
    float* __restrict__ out, int n)
{
    __shared__ __align__(16) char  fkT[WPB][NK * ROWB];   // 3 x 8704 B
    __shared__ __align__(16) float rbuf[WPB][NK];         // 3 x  128 B

    const int w    = threadIdx.x >> 6;   // wave id in block, 0..2
    const int lane = threadIdx.x & 63;
    const int l31  = lane & 31;
    const int hf   = lane >> 5;
    const int g    = lane >> 4;        // gather row group 0..3
    const int m    = lane & 15;        // gather 16B chunk 0..15
    const int pbase = (lane & 32) + ((lane & 32) >> 3);

    char* fkw = &fkT[w][0];

    // loop-invariant addresses
    const int d0 = 2 * lane;
    const float2 bv = *reinterpret_cast<const float2*>(bias + d0);
    const float4* rb = reinterpret_cast<const float4*>(&rbuf[w][0]);
    // coalesced-write vaddr: row k=4i+g, cols 4m..4m+3 -> 272k + 16*((m+4g)&15)
    const int wbase = ROWB * g + 16 * ((m + 4 * g) & 15);
    // frag-read base (row l31) and rolling rotated column
    const int fbase = ROWB * l31;
    const int uc0   = 4 * hf + 16 * (l31 & 3);       // dword col bias
    // epilogue vaddrs: col lane of row k stored at ((lane + 16*(k&3))&63)
    int eaddr[4];
#pragma unroll
    for (int p = 0; p < 4; ++p) eaddr[p] = 4 * ((lane + 16 * p) & 63);

    const int stride = gridDim.x * WPB;
    int nd = blockIdx.x * WPB + w;
    if (nd >= n) return;

    // ---- prologue: first node's idx/tkw + coalesced gather ----
    int   vid = idx[(size_t)nd * NK + l31];
    float tw  = tkw[(size_t)nd * NK + l31];
    int   mkc = (vid < 0) ? 1 : 0;
    float wc  = mkc ? 0.0f : tw;
    half8 gb[8];
    {
        int idr = mkc ? 0 : vid;                     // per-lane (k=l31) id
#pragma unroll
        for (int i = 0; i < 8; ++i) {
            int idg = __shfl(idr, 4 * i + g, 64);    // row 4i+g's id
            gb[i] = *reinterpret_cast<const half8*>(
                hq + (size_t)idg * DIM + 8 * m);     // lane's 16B of that row
        }
    }

    while (true) {
        const int  ndn = nd + stride;
        const bool hn  = ndn < n;

        // pipeline stage 1: next node's idx/tkw
        int vid_n = 0; float tw_n = 0.0f;
        if (hn) {
            vid_n = idx[(size_t)ndn * NK + l31];
            tw_n  = tkw[(size_t)ndn * NK + l31];
        }

        // ---- coalesced write of gathered rows into rotated LDS ----
#pragma unroll
        for (int i = 0; i < 8; ++i)
            *reinterpret_cast<half8*>(&fkw[1088 * i + wbase]) = gb[i];

        // ---- frag reads (row l31, rotated) + gram MFMA + fdot2 sq ----
        f32x16 acc;
#pragma unroll
        for (int i = 0; i < 16; ++i) acc[i] = 0.0f;
        float sqp = 0.0f;
        int u = uc0;
#pragma unroll
        for (int s = 0; s < 8; ++s) {
            half8 fr = *reinterpret_cast<const half8*>(&fkw[fbase + 4 * (u & 63)]);
            u += 8;
            acc = __builtin_amdgcn_mfma_f32_32x32x16_f16(fr, fr, acc, 0, 0, 0);
            const half2v* p2 = reinterpret_cast<const half2v*>(&fr);
#pragma unroll
            for (int q = 0; q < 4; ++q)
                sqp = __builtin_amdgcn_fdot2(p2[q], p2[q], sqp, false);
        }
        float sq = sqp + __shfl_xor(sqp, 32, 64);

        // pipeline stage 2: next node's coalesced gather (in flight across
        // the dagg/softmax/epilogue tail)
        const int mk_n = (vid_n < 0) ? 1 : 0;
        half8 gb_n[8];
        if (hn) {
            int idr_n = mk_n ? 0 : vid_n;
#pragma unroll
            for (int i = 0; i < 8; ++i) {
                int idg = __shfl(idr_n, 4 * i + g, 64);
                gb_n[i] = *reinterpret_cast<const half8*>(
                    hq + (size_t)idg * DIM + 8 * m);
            }
        }

        // 9th MFMA: acc += -(sq_m + sq_c)/2 -> acc = -d2/2 (hi/lo f16 split)
        {
            _Float16 shi = (_Float16)sq;
            _Float16 slo = (_Float16)(sq - (float)shi);
            _Float16 nh  = (_Float16)(-0.5f * (float)shi);
            _Float16 nl  = (_Float16)(-0.5f * (float)slo);
            _Float16 z   = (_Float16)0.0f, one = (_Float16)1.0f;
            half8 aext = {z, z, z, z, z, z, z, z};
            half8 bext = {z, z, z, z, z, z, z, z};
            if (hf == 0) {
                aext[0] = nh;  aext[1] = nl;  aext[2] = one; aext[3] = one;
                bext[0] = one; bext[1] = one; bext[2] = nh;  bext[3] = nl;
            }
            acc = __builtin_amdgcn_mfma_f32_32x32x16_f16(aext, bext, acc, 0, 0, 0);
        }

        // dagg[c=l31] = sum_m w[m]*dist[m][c]; w[rD] via bpermute; 4-way tree
        float pt[4] = {0.0f, 0.0f, 0.0f, 0.0f};
#pragma unroll
        for (int reg = 0; reg < 16; ++reg) {
            const int c = (reg & 3) + 8 * (reg >> 2);
            float wr = __shfl(wc, pbase + c, 64);        // w[c + 4hf]
            float d2 = fmaxf(-(acc[reg] + acc[reg]), 0.0f);
            float ds = (d2 > 1e-4f) ? __builtin_amdgcn_sqrtf(d2) : 0.0f;
            pt[reg & 3] = fmaf(wr, ds, pt[reg & 3]);
        }
        float part = (pt[0] + pt[1]) + (pt[2] + pt[3]);
        float sA = part + __shfl_xor(part, 32, 64);
        if (mkc || !(sA < 3.4028235e38f)) sA = 3.4028235e38f;

        // fused softmax + weight correction: r = e*w / sum(e*w)
        float x  = -sA;
        float mx = x;
#pragma unroll
        for (int o = 16; o > 0; o >>= 1) mx = fmaxf(mx, __shfl_xor(mx, o, 32));
        float t  = __expf(x - mx) * wc;      // masked lanes: w=0 -> t=0
        float st = t;
#pragma unroll
        for (int o = 16; o > 0; o >>= 1) st += __shfl_xor(st, o, 32);
        float r = t * __builtin_amdgcn_rcpf(st);

        // broadcast r via LDS (dup-write from both halves; benign)
        rbuf[w][l31] = r;

        // ---- epilogue: out[d] = sum_k r_k * fk[k][d]; 2 dims/lane ----
        // lane's dword (cols d0,d0+1) of row k at eaddr[k&3] + 272k (imm).
        float o0 = 0.0f, o1 = 0.0f;
#pragma unroll
        for (int q = 0; q < 8; ++q) {
            float4 rv = rb[q];
            half2v h0 = *reinterpret_cast<const half2v*>(&fkw[ROWB * (4 * q + 0) + eaddr[0]]);
            half2v h1 = *reinterpret_cast<const half2v*>(&fkw[ROWB * (4 * q + 1) + eaddr[1]]);
            half2v h2 = *reinterpret_cast<const half2v*>(&fkw[ROWB * (4 * q + 2) + eaddr[2]]);
            half2v h3 = *reinterpret_cast<const half2v*>(&fkw[ROWB * (4 * q + 3) + eaddr[3]]);
            o0 = fmaf(rv.x, (float)h0[0], o0); o1 = fmaf(rv.x, (float)h0[1], o1);
            o0 = fmaf(rv.y, (float)h1[0], o0); o1 = fmaf(rv.y, (float)h1[1], o1);
            o0 = fmaf(rv.z, (float)h2[0], o0); o1 = fmaf(rv.z, (float)h2[1], o1);
            o0 = fmaf(rv.w, (float)h3[0], o0); o1 = fmaf(rv.w, (float)h3[1], o1);
        }
        float2 ov = { o0 + bv.x, o1 + bv.y };
        *reinterpret_cast<float2*>(out + (size_t)nd * DIM + d0) = ov;

        if (!hn) break;
        // rotate pipeline registers
        nd  = ndn;
        mkc = mk_n;
        wc  = mk_n ? 0.0f : tw_n;
#pragma unroll
        for (int i = 0; i < 8; ++i) gb[i] = gb_n[i];
    }
}

extern "C" void kernel_launch(void* const* d_in, const int* in_sizes, int n_in,
                              void* d_out, int out_size, void* d_ws, size_t ws_size,
                              hipStream_t stream) {
    const float* feat = (const float*)d_in[0];
    const float* W    = (const float*)d_in[1];
    const float* bias = (const float*)d_in[2];
    const float* tkw  = (const float*)d_in[3];
    const int*   idx  = (const int*)d_in[4];
    float* out = (float*)d_out;

    const int n = in_sizes[0] / DIM;                       // 50000
    _Float16* hq = (_Float16*)d_ws;                        // n*128*2 = 12.8 MB

    const int sblocks = (n + 4 * WPB - 1) / (4 * WPB);     // 4167 (softk)

    // DIAGNOSTIC: gemm launched twice (idempotent; identical hq bytes).
    // delta(dur_us) vs r27 = one (gemm + boundary-gap) — the unobservable.
    gemm128<<<GEMM_BLOCKS, 256, 0, stream>>>(feat, W, hq, n);
    gemm128<<<GEMM_BLOCKS, 256, 0, stream>>>(feat, W, hq, n);
    softk<<<sblocks, 192, 0, stream>>>(hq, bias, tkw, idx, out, n);
}

// Round 17
// 144.762 us; speedup vs baseline: 1.0967x; 1.0967x over previous
//
#include <hip/hip_runtime.h>
#include <math.h>

// SoftKConv, round 30.
// r29 differential landed: double-gemm cost only +12.9us => gemm+boundary
// ~= 13us, H2 CONFIRMED (gemm ~6-10us, near roofline; 4 rounds of gemm
// tuning were chasing a ghost). Books: 145.9 = 13 + softk 63.7 + fixed 7 +
// ~62us UNACCOUNTED. Not per-kernel (r29 proves), not gemm->gemm WAW.
// Survivors: (a) harness reset dispatches in-window (uncontrollable), or
// (b) the dependent gemm->softk boundary: 12.8MB DIRTY hq in 8 non-coherent
// XCD L2s must write back before softk's cross-XCD gathers (r18's coop
// disaster = same mechanism).
// r30: NON-TEMPORAL stores for gemm's Hq and softk's out — bit-identical
// values, but lines don't sit dirty in L2, so the boundary flush is ~empty.
// (b) => ~95-115us. (a) => flat ~146 and we've found the floor's owner.
// Math/layout otherwise = r27 exactly.

typedef __attribute__((ext_vector_type(2)))  _Float16 half2v;
typedef __attribute__((ext_vector_type(4)))  _Float16 half4v;
typedef __attribute__((ext_vector_type(8)))  _Float16 half8;
typedef __attribute__((ext_vector_type(2)))  float    f32x2;
typedef __attribute__((ext_vector_type(16))) float    f32x16;

#define NK   32
#define DIM  128
// softk LDS row stride 272 B (64 dwords used + 4 pad); rotation 16*(k&3) dwords.
#define ROWB 272
// waves (independent node streams) per softk workgroup
#define WPB  3
// persistent gemm grid
#define GEMM_BLOCKS 512

// ---------------- Kernel 1: h = feat @ W -> f16, persistent MFMA -----------
__global__ __launch_bounds__(256) void gemm128(
    const float* __restrict__ A, const float* __restrict__ W,
    _Float16* __restrict__ Hq, int n)
{
    // 32 rows x 132 floats (528 B stride: 16B-aligned, pad kills pow2 stride)
    __shared__ __align__(16) char smem[32 * 528];          // 16896 B

    const int tid  = threadIdx.x;
    const int lane = tid & 63;
    const int l31  = lane & 31;
    const int hf   = lane >> 5;
    const int t    = tid >> 6;                // col-tile 0..3
    const int col  = l31 + 32 * t;            // output col 0..127

    // staging thread mapping (8 threads/row)
    const int sr = tid >> 3;                  // 0..31
    const int sc = tid & 7;                   // 16B chunk group

    // ---- af fragments from W: ONCE per block (amortized over tiles) ----
    half8 af[8];
#pragma unroll
    for (int s = 0; s < 8; ++s) {
        const float* wp = W + (size_t)(16 * s + 8 * hf) * 128 + col;
#pragma unroll
        for (int e = 0; e < 8; ++e)
            af[s][e] = (_Float16)wp[(size_t)e * 128];
    }

    const int ntiles = (n + 31) >> 5;
    for (int tile = blockIdx.x; tile < ntiles; tile += GEMM_BLOCKS) {
        const int row0 = tile * 32;

        __syncthreads();   // prior iteration's smem readers done

        // ---- stage feat tile: fully coalesced (8 threads/row, 128B runs) --
        {
            int rr = row0 + sr; if (rr >= n) rr = n - 1;
            const float* src = A + (size_t)rr * 128 + 4 * sc;
            char* dst = smem + sr * 528 + 16 * sc;
#pragma unroll
            for (int i = 0; i < 4; ++i) {
                float4 v = *reinterpret_cast<const float4*>(src + 32 * i);
                *reinterpret_cast<float4*>(dst + 128 * i) = v;
            }
        }

        __syncthreads();

        // ---- bf from LDS (row l31, 16B-aligned) + MFMA ----
        f32x16 acc;
#pragma unroll
        for (int i = 0; i < 16; ++i) acc[i] = 0.0f;

        const char* myrow = smem + l31 * 528 + 32 * hf;    // float col 8*hf
#pragma unroll
        for (int s = 0; s < 8; ++s) {
            float4 b0 = *reinterpret_cast<const float4*>(myrow + 64 * s);
            float4 b1 = *reinterpret_cast<const float4*>(myrow + 64 * s + 16);
            half8 bf;
            bf[0] = (_Float16)b0.x; bf[1] = (_Float16)b0.y;
            bf[2] = (_Float16)b0.z; bf[3] = (_Float16)b0.w;
            bf[4] = (_Float16)b1.x; bf[5] = (_Float16)b1.y;
            bf[6] = (_Float16)b1.z; bf[7] = (_Float16)b1.w;
            acc = __builtin_amdgcn_mfma_f32_32x32x16_f16(af[s], bf, acc, 0, 0, 0);
        }

        __syncthreads();                                   // done reading tile

        // ---- stage output f16 tile in LDS (32 rows x 272 B stride) ----
        {
            char* orow = smem + l31 * 272 + 64 * t + 8 * hf;
#pragma unroll
            for (int g = 0; g < 4; ++g) {
                half4v hv;
#pragma unroll
                for (int q = 0; q < 4; ++q) hv[q] = (_Float16)acc[4 * g + q];
                *reinterpret_cast<half4v*>(orow + 16 * g) = hv;
            }
        }

        __syncthreads();

        // ---- coalesced NON-TEMPORAL row stores (no dirty L2 at boundary) --
        {
            const int orow = row0 + sr;
            if (orow < n) {
                const char* srcl = smem + sr * 272 + 16 * sc;
                _Float16*   dst  = Hq + (size_t)orow * 128 + 8 * sc;
#pragma unroll
                for (int i = 0; i < 2; ++i) {
                    half8 v = *reinterpret_cast<const half8*>(srcl + 128 * i);
                    __builtin_nontemporal_store(
                        v, reinterpret_cast<half8*>(dst + 64 * i));
                }
            }
        }
    }
}

// ---------------- Kernel 2: per-node soft medoid, pipelined ----------------
// 192 threads = 3 independent waves/block, each wave = its own node stream
// with next-node prefetch. No barriers; per-wave LDS slices are disjoint.
__global__ __launch_bounds__(192, 4) void softk(
    const _Float16* __restrict__ hq, const float* __restrict__ bias,
    const float* __restrict__ tkw, const int* __restrict__ idx,
    float* __restrict__ out, int n)
{
    __shared__ __align__(16) char  fkT[WPB][NK * ROWB];   // 3 x 8704 B
    __shared__ __align__(16) float rbuf[WPB][NK];         // 3 x  128 B

    const int w    = threadIdx.x >> 6;   // wave id in block, 0..2
    const int lane = threadIdx.x & 63;
    const int l31  = lane & 31;
    const int hf   = lane >> 5;
    const int g    = lane >> 4;        // gather row group 0..3
    const int m    = lane & 15;        // gather 16B chunk 0..15
    const int pbase = (lane & 32) + ((lane & 32) >> 3);

    char* fkw = &fkT[w][0];

    // loop-invariant addresses
    const int d0 = 2 * lane;
    const float2 bv = *reinterpret_cast<const float2*>(bias + d0);
    const float4* rb = reinterpret_cast<const float4*>(&rbuf[w][0]);
    // coalesced-write vaddr: row k=4i+g, cols 4m..4m+3 -> 272k + 16*((m+4g)&15)
    const int wbase = ROWB * g + 16 * ((m + 4 * g) & 15);
    // frag-read base (row l31) and rolling rotated column
    const int fbase = ROWB * l31;
    const int uc0   = 4 * hf + 16 * (l31 & 3);       // dword col bias
    // epilogue vaddrs: col lane of row k stored at ((lane + 16*(k&3))&63)
    int eaddr[4];
#pragma unroll
    for (int p = 0; p < 4; ++p) eaddr[p] = 4 * ((lane + 16 * p) & 63);

    const int stride = gridDim.x * WPB;
    int nd = blockIdx.x * WPB + w;
    if (nd >= n) return;

    // ---- prologue: first node's idx/tkw + coalesced gather ----
    int   vid = idx[(size_t)nd * NK + l31];
    float tw  = tkw[(size_t)nd * NK + l31];
    int   mkc = (vid < 0) ? 1 : 0;
    float wc  = mkc ? 0.0f : tw;
    half8 gb[8];
    {
        int idr = mkc ? 0 : vid;                     // per-lane (k=l31) id
#pragma unroll
        for (int i = 0; i < 8; ++i) {
            int idg = __shfl(idr, 4 * i + g, 64);    // row 4i+g's id
            gb[i] = *reinterpret_cast<const half8*>(
                hq + (size_t)idg * DIM + 8 * m);     // lane's 16B of that row
        }
    }

    while (true) {
        const int  ndn = nd + stride;
        const bool hn  = ndn < n;

        // pipeline stage 1: next node's idx/tkw
        int vid_n = 0; float tw_n = 0.0f;
        if (hn) {
            vid_n = idx[(size_t)ndn * NK + l31];
            tw_n  = tkw[(size_t)ndn * NK + l31];
        }

        // ---- coalesced write of gathered rows into rotated LDS ----
#pragma unroll
        for (int i = 0; i < 8; ++i)
            *reinterpret_cast<half8*>(&fkw[1088 * i + wbase]) = gb[i];

        // ---- frag reads (row l31, rotated) + gram MFMA + fdot2 sq ----
        f32x16 acc;
#pragma unroll
        for (int i = 0; i < 16; ++i) acc[i] = 0.0f;
        float sqp = 0.0f;
        int u = uc0;
#pragma unroll
        for (int s = 0; s < 8; ++s) {
            half8 fr = *reinterpret_cast<const half8*>(&fkw[fbase + 4 * (u & 63)]);
            u += 8;
            acc = __builtin_amdgcn_mfma_f32_32x32x16_f16(fr, fr, acc, 0, 0, 0);
            const half2v* p2 = reinterpret_cast<const half2v*>(&fr);
#pragma unroll
            for (int q = 0; q < 4; ++q)
                sqp = __builtin_amdgcn_fdot2(p2[q], p2[q], sqp, false);
        }
        float sq = sqp + __shfl_xor(sqp, 32, 64);

        // pipeline stage 2: next node's coalesced gather (in flight across
        // the dagg/softmax/epilogue tail)
        const int mk_n = (vid_n < 0) ? 1 : 0;
        half8 gb_n[8];
        if (hn) {
            int idr_n = mk_n ? 0 : vid_n;
#pragma unroll
            for (int i = 0; i < 8; ++i) {
                int idg = __shfl(idr_n, 4 * i + g, 64);
                gb_n[i] = *reinterpret_cast<const half8*>(
                    hq + (size_t)idg * DIM + 8 * m);
            }
        }

        // 9th MFMA: acc += -(sq_m + sq_c)/2 -> acc = -d2/2 (hi/lo f16 split)
        {
            _Float16 shi = (_Float16)sq;
            _Float16 slo = (_Float16)(sq - (float)shi);
            _Float16 nh  = (_Float16)(-0.5f * (float)shi);
            _Float16 nl  = (_Float16)(-0.5f * (float)slo);
            _Float16 z   = (_Float16)0.0f, one = (_Float16)1.0f;
            half8 aext = {z, z, z, z, z, z, z, z};
            half8 bext = {z, z, z, z, z, z, z, z};
            if (hf == 0) {
                aext[0] = nh;  aext[1] = nl;  aext[2] = one; aext[3] = one;
                bext[0] = one; bext[1] = one; bext[2] = nh;  bext[3] = nl;
            }
            acc = __builtin_amdgcn_mfma_f32_32x32x16_f16(aext, bext, acc, 0, 0, 0);
        }

        // dagg[c=l31] = sum_m w[m]*dist[m][c]; w[rD] via bpermute; 4-way tree
        float pt[4] = {0.0f, 0.0f, 0.0f, 0.0f};
#pragma unroll
        for (int reg = 0; reg < 16; ++reg) {
            const int c = (reg & 3) + 8 * (reg >> 2);
            float wr = __shfl(wc, pbase + c, 64);        // w[c + 4hf]
            float d2 = fmaxf(-(acc[reg] + acc[reg]), 0.0f);
            float ds = (d2 > 1e-4f) ? __builtin_amdgcn_sqrtf(d2) : 0.0f;
            pt[reg & 3] = fmaf(wr, ds, pt[reg & 3]);
        }
        float part = (pt[0] + pt[1]) + (pt[2] + pt[3]);
        float sA = part + __shfl_xor(part, 32, 64);
        if (mkc || !(sA < 3.4028235e38f)) sA = 3.4028235e38f;

        // fused softmax + weight correction: r = e*w / sum(e*w)
        float x  = -sA;
        float mx = x;
#pragma unroll
        for (int o = 16; o > 0; o >>= 1) mx = fmaxf(mx, __shfl_xor(mx, o, 32));
        float t  = __expf(x - mx) * wc;      // masked lanes: w=0 -> t=0
        float st = t;
#pragma unroll
        for (int o = 16; o > 0; o >>= 1) st += __shfl_xor(st, o, 32);
        float r = t * __builtin_amdgcn_rcpf(st);

        // broadcast r via LDS (dup-write from both halves; benign)
        rbuf[w][l31] = r;

        // ---- epilogue: out[d] = sum_k r_k * fk[k][d]; 2 dims/lane ----
        // lane's dword (cols d0,d0+1) of row k at eaddr[k&3] + 272k (imm).
        float o0 = 0.0f, o1 = 0.0f;
#pragma unroll
        for (int q = 0; q < 8; ++q) {
            float4 rv = rb[q];
            half2v h0 = *reinterpret_cast<const half2v*>(&fkw[ROWB * (4 * q + 0) + eaddr[0]]);
            half2v h1 = *reinterpret_cast<const half2v*>(&fkw[ROWB * (4 * q + 1) + eaddr[1]]);
            half2v h2 = *reinterpret_cast<const half2v*>(&fkw[ROWB * (4 * q + 2) + eaddr[2]]);
            half2v h3 = *reinterpret_cast<const half2v*>(&fkw[ROWB * (4 * q + 3) + eaddr[3]]);
            o0 = fmaf(rv.x, (float)h0[0], o0); o1 = fmaf(rv.x, (float)h0[1], o1);
            o0 = fmaf(rv.y, (float)h1[0], o0); o1 = fmaf(rv.y, (float)h1[1], o1);
            o0 = fmaf(rv.z, (float)h2[0], o0); o1 = fmaf(rv.z, (float)h2[1], o1);
            o0 = fmaf(rv.w, (float)h3[0], o0); o1 = fmaf(rv.w, (float)h3[1], o1);
        }
        f32x2 ov; ov[0] = o0 + bv.x; ov[1] = o1 + bv.y;
        __builtin_nontemporal_store(
            ov, reinterpret_cast<f32x2*>(out + (size_t)nd * DIM + d0));

        if (!hn) break;
        // rotate pipeline registers
        nd  = ndn;
        mkc = mk_n;
        wc  = mk_n ? 0.0f : tw_n;
#pragma unroll
        for (int i = 0; i < 8; ++i) gb[i] = gb_n[i];
    }
}

extern "C" void kernel_launch(void* const* d_in, const int* in_sizes, int n_in,
                              void* d_out, int out_size, void* d_ws, size_t ws_size,
                              hipStream_t stream) {
    const float* feat = (const float*)d_in[0];
    const float* W    = (const float*)d_in[1];
    const float* bias = (const float*)d_in[2];
    const float* tkw  = (const float*)d_in[3];
    const int*   idx  = (const int*)d_in[4];
    float* out = (float*)d_out;

    const int n = in_sizes[0] / DIM;                       // 50000
    _Float16* hq = (_Float16*)d_ws;                        // n*128*2 = 12.8 MB

    const int sblocks = (n + 4 * WPB - 1) / (4 * WPB);     // 4167 (softk)

    gemm128<<<GEMM_BLOCKS, 256, 0, stream>>>(feat, W, hq, n);
    softk<<<sblocks, 192, 0, stream>>>(hq, bias, tkw, idx, out, n);
}

// Round 23
// 142.227 us; speedup vs baseline: 1.1163x; 1.0178x over previous
//
#include <hip/hip_runtime.h>
#include <math.h>

// SoftKConv, round 36 (= r31..r35 resubmitted; all prior benches died on
// GPU acquisition timeout — no data, kernel untested on HW).
// r30 post-mortem: NT stores null (145.9->144.8). Ledger: gemm+boundary
// 12.9us (r29 differential), softk ~64, ~68us invariant under EVERY knob
// (launch count r20, fusion r18, persistence r27, occupancy r14, NT r30)
// => harness-owned floor. Controllable budget = softk + gemm only.
// r31..r36: (1) REVERT softk to r13's 1-wave/64-thread blocks — measured
// 62.6-62.8 vs the r14 3-wave packing's 63.5-65.3 (packing cost ~1.5-2us,
// no benefit). (2) dagg w-broadcast: 16 __shfl (VALU) -> 16 ds_read_b32
// broadcasts from wc stashed in fkT's 16B row-pad (bytes 256..271 per 272B
// row; disjoint from gather writes <=256, frag reads <=256, epilogue reads
// <=256). Addr = base 1088*hf+256 + imm 272*c => ~zero VALU. Bit-identical
// values. gemm/NT = r30 exactly.

typedef __attribute__((ext_vector_type(2)))  _Float16 half2v;
typedef __attribute__((ext_vector_type(4)))  _Float16 half4v;
typedef __attribute__((ext_vector_type(8)))  _Float16 half8;
typedef __attribute__((ext_vector_type(2)))  float    f32x2;
typedef __attribute__((ext_vector_type(16))) float    f32x16;

#define NK   32
#define DIM  128
// softk LDS row stride 272 B (64 dwords used + 4 pad); rotation 16*(k&3) dwords.
#define ROWB 272
// persistent gemm grid
#define GEMM_BLOCKS 512

// ---------------- Kernel 1: h = feat @ W -> f16, persistent MFMA -----------
__global__ __launch_bounds__(256) void gemm128(
    const float* __restrict__ A, const float* __restrict__ W,
    _Float16* __restrict__ Hq, int n)
{
    // 32 rows x 132 floats (528 B stride: 16B-aligned, pad kills pow2 stride)
    __shared__ __align__(16) char smem[32 * 528];          // 16896 B

    const int tid  = threadIdx.x;
    const int lane = tid & 63;
    const int l31  = lane & 31;
    const int hf   = lane >> 5;
    const int t    = tid >> 6;                // col-tile 0..3
    const int col  = l31 + 32 * t;            // output col 0..127

    // staging thread mapping (8 threads/row)
    const int sr = tid >> 3;                  // 0..31
    const int sc = tid & 7;                   // 16B chunk group

    // ---- af fragments from W: ONCE per block (amortized over tiles) ----
    half8 af[8];
#pragma unroll
    for (int s = 0; s < 8; ++s) {
        const float* wp = W + (size_t)(16 * s + 8 * hf) * 128 + col;
#pragma unroll
        for (int e = 0; e < 8; ++e)
            af[s][e] = (_Float16)wp[(size_t)e * 128];
    }

    const int ntiles = (n + 31) >> 5;
    for (int tile = blockIdx.x; tile < ntiles; tile += GEMM_BLOCKS) {
        const int row0 = tile * 32;

        __syncthreads();   // prior iteration's smem readers done

        // ---- stage feat tile: fully coalesced (8 threads/row, 128B runs) --
        {
            int rr = row0 + sr; if (rr >= n) rr = n - 1;
            const float* src = A + (size_t)rr * 128 + 4 * sc;
            char* dst = smem + sr * 528 + 16 * sc;
#pragma unroll
            for (int i = 0; i < 4; ++i) {
                float4 v = *reinterpret_cast<const float4*>(src + 32 * i);
                *reinterpret_cast<float4*>(dst + 128 * i) = v;
            }
        }

        __syncthreads();

        // ---- bf from LDS (row l31, 16B-aligned) + MFMA ----
        f32x16 acc;
#pragma unroll
        for (int i = 0; i < 16; ++i) acc[i] = 0.0f;

        const char* myrow = smem + l31 * 528 + 32 * hf;    // float col 8*hf
#pragma unroll
        for (int s = 0; s < 8; ++s) {
            float4 b0 = *reinterpret_cast<const float4*>(myrow + 64 * s);
            float4 b1 = *reinterpret_cast<const float4*>(myrow + 64 * s + 16);
            half8 bf;
            bf[0] = (_Float16)b0.x; bf[1] = (_Float16)b0.y;
            bf[2] = (_Float16)b0.z; bf[3] = (_Float16)b0.w;
            bf[4] = (_Float16)b1.x; bf[5] = (_Float16)b1.y;
            bf[6] = (_Float16)b1.z; bf[7] = (_Float16)b1.w;
            acc = __builtin_amdgcn_mfma_f32_32x32x16_f16(af[s], bf, acc, 0, 0, 0);
        }

        __syncthreads();                                   // done reading tile

        // ---- stage output f16 tile in LDS (32 rows x 272 B stride) ----
        {
            char* orow = smem + l31 * 272 + 64 * t + 8 * hf;
#pragma unroll
            for (int g = 0; g < 4; ++g) {
                half4v hv;
#pragma unroll
                for (int q = 0; q < 4; ++q) hv[q] = (_Float16)acc[4 * g + q];
                *reinterpret_cast<half4v*>(orow + 16 * g) = hv;
            }
        }

        __syncthreads();

        // ---- coalesced NON-TEMPORAL row stores ----
        {
            const int orow = row0 + sr;
            if (orow < n) {
                const char* srcl = smem + sr * 272 + 16 * sc;
                _Float16*   dst  = Hq + (size_t)orow * 128 + 8 * sc;
#pragma unroll
                for (int i = 0; i < 2; ++i) {
                    half8 v = *reinterpret_cast<const half8*>(srcl + 128 * i);
                    __builtin_nontemporal_store(
                        v, reinterpret_cast<half8*>(dst + 64 * i));
                }
            }
        }
    }
}

// ---------------- Kernel 2: per-node soft medoid, pipelined ----------------
// 64 threads = 1 wave/block (r13 structure — fastest measured); ~4 nodes/wave
// with next-node prefetch. dagg weights broadcast via fkT row-pad (LGKM pipe)
// instead of 16 VALU shuffles.
__global__ __launch_bounds__(64, 4) void softk(
    const _Float16* __restrict__ hq, const float* __restrict__ bias,
    const float* __restrict__ tkw, const int* __restrict__ idx,
    float* __restrict__ out, int n)
{
    __shared__ __align__(16) char  fkT[NK * ROWB];   // 8704 B, rotated rows
    __shared__ __align__(16) float rbuf[NK];         //  128 B

    const int lane = threadIdx.x;
    const int l31  = lane & 31;
    const int hf   = lane >> 5;
    const int g    = lane >> 4;        // gather row group 0..3
    const int m    = lane & 15;        // gather 16B chunk 0..15

    // loop-invariant addresses
    const int d0 = 2 * lane;
    const float2 bv = *reinterpret_cast<const float2*>(bias + d0);
    const float4* rb = reinterpret_cast<const float4*>(&rbuf[0]);
    // coalesced-write vaddr: row k=4i+g, cols 4m..4m+3 -> 272k + 16*((m+4g)&15)
    const int wbase = ROWB * g + 16 * ((m + 4 * g) & 15);
    // frag-read base (row l31) and rolling rotated column
    const int fbase = ROWB * l31;
    const int uc0   = 4 * hf + 16 * (l31 & 3);       // dword col bias
    // w-broadcast base: pad dword of row (c + 4hf) at 272*(c+4hf)+256
    const int wpadb = 1088 * hf + 256;
    // epilogue vaddrs: col lane of row k stored at ((lane + 16*(k&3))&63)
    int eaddr[4];
#pragma unroll
    for (int p = 0; p < 4; ++p) eaddr[p] = 4 * ((lane + 16 * p) & 63);

    const int stride = gridDim.x;
    int nd = blockIdx.x;
    if (nd >= n) return;

    // ---- prologue: first node's idx/tkw + coalesced gather ----
    int   vid = idx[(size_t)nd * NK + l31];
    float tw  = tkw[(size_t)nd * NK + l31];
    int   mkc = (vid < 0) ? 1 : 0;
    float wc  = mkc ? 0.0f : tw;
    half8 gb[8];
    {
        int idr = mkc ? 0 : vid;                     // per-lane (k=l31) id
#pragma unroll
        for (int i = 0; i < 8; ++i) {
            int idg = __shfl(idr, 4 * i + g, 64);    // row 4i+g's id
            gb[i] = *reinterpret_cast<const half8*>(
                hq + (size_t)idg * DIM + 8 * m);     // lane's 16B of that row
        }
    }

    while (true) {
        const int  ndn = nd + stride;
        const bool hn  = ndn < n;

        // pipeline stage 1: next node's idx/tkw
        int vid_n = 0; float tw_n = 0.0f;
        if (hn) {
            vid_n = idx[(size_t)ndn * NK + l31];
            tw_n  = tkw[(size_t)ndn * NK + l31];
        }

        // ---- coalesced write of gathered rows into rotated LDS ----
#pragma unroll
        for (int i = 0; i < 8; ++i)
            *reinterpret_cast<half8*>(&fkT[1088 * i + wbase]) = gb[i];
        // stash w[m] in row m's pad dword (both halves write same value)
        *reinterpret_cast<float*>(&fkT[ROWB * l31 + 256]) = wc;

        // ---- frag reads (row l31, rotated) + gram MFMA + fdot2 sq ----
        f32x16 acc;
#pragma unroll
        for (int i = 0; i < 16; ++i) acc[i] = 0.0f;
        float sqp = 0.0f;
        int u = uc0;
#pragma unroll
        for (int s = 0; s < 8; ++s) {
            half8 fr = *reinterpret_cast<const half8*>(&fkT[fbase + 4 * (u & 63)]);
            u += 8;
            acc = __builtin_amdgcn_mfma_f32_32x32x16_f16(fr, fr, acc, 0, 0, 0);
            const half2v* p2 = reinterpret_cast<const half2v*>(&fr);
#pragma unroll
            for (int q = 0; q < 4; ++q)
                sqp = __builtin_amdgcn_fdot2(p2[q], p2[q], sqp, false);
        }
        float sq = sqp + __shfl_xor(sqp, 32, 64);

        // pipeline stage 2: next node's coalesced gather (in flight across
        // the dagg/softmax/epilogue tail)
        const int mk_n = (vid_n < 0) ? 1 : 0;
        half8 gb_n[8];
        if (hn) {
            int idr_n = mk_n ? 0 : vid_n;
#pragma unroll
            for (int i = 0; i < 8; ++i) {
                int idg = __shfl(idr_n, 4 * i + g, 64);
                gb_n[i] = *reinterpret_cast<const half8*>(
                    hq + (size_t)idg * DIM + 8 * m);
            }
        }

        // 9th MFMA: acc += -(sq_m + sq_c)/2 -> acc = -d2/2 (hi/lo f16 split)
        {
            _Float16 shi = (_Float16)sq;
            _Float16 slo = (_Float16)(sq - (float)shi);
            _Float16 nh  = (_Float16)(-0.5f * (float)shi);
            _Float16 nl  = (_Float16)(-0.5f * (float)slo);
            _Float16 z   = (_Float16)0.0f, one = (_Float16)1.0f;
            half8 aext = {z, z, z, z, z, z, z, z};
            half8 bext = {z, z, z, z, z, z, z, z};
            if (hf == 0) {
                aext[0] = nh;  aext[1] = nl;  aext[2] = one; aext[3] = one;
                bext[0] = one; bext[1] = one; bext[2] = nh;  bext[3] = nl;
            }
            acc = __builtin_amdgcn_mfma_f32_32x32x16_f16(aext, bext, acc, 0, 0, 0);
        }

        // dagg[c=l31] = sum_m w[m]*dist[m][c]; w[m] via LDS pad broadcast
        float pt[4] = {0.0f, 0.0f, 0.0f, 0.0f};
#pragma unroll
        for (int reg = 0; reg < 16; ++reg) {
            const int c = (reg & 3) + 8 * (reg >> 2);
            float wr = *reinterpret_cast<const float*>(&fkT[wpadb + 272 * c]);
            float d2 = fmaxf(-(acc[reg] + acc[reg]), 0.0f);
            float ds = (d2 > 1e-4f) ? __builtin_amdgcn_sqrtf(d2) : 0.0f;
            pt[reg & 3] = fmaf(wr, ds, pt[reg & 3]);
        }
        float part = (pt[0] + pt[1]) + (pt[2] + pt[3]);
        float sA = part + __shfl_xor(part, 32, 64);
        if (mkc || !(sA < 3.4028235e38f)) sA = 3.4028235e38f;

        // fused softmax + weight correction: r = e*w / sum(e*w)
        float x  = -sA;
        float mx = x;
#pragma unroll
        for (int o = 16; o > 0; o >>= 1) mx = fmaxf(mx, __shfl_xor(mx, o, 32));
        float t  = __expf(x - mx) * wc;      // masked lanes: w=0 -> t=0
        float st = t;
#pragma unroll
        for (int o = 16; o > 0; o >>= 1) st += __shfl_xor(st, o, 32);
        float r = t * __builtin_amdgcn_rcpf(st);

        // broadcast r via LDS (dup-write from both halves; benign)
        rbuf[l31] = r;

        // ---- epilogue: out[d] = sum_k r_k * fk[k][d]; 2 dims/lane ----
        // lane's dword (cols d0,d0+1) of row k at eaddr[k&3] + 272k (imm).
        float o0 = 0.0f, o1 = 0.0f;
#pragma unroll
        for (int q = 0; q < 8; ++q) {
            float4 rv = rb[q];
            half2v h0 = *reinterpret_cast<const half2v*>(&fkT[ROWB * (4 * q + 0) + eaddr[0]]);
            half2v h1 = *reinterpret_cast<const half2v*>(&fkT[ROWB * (4 * q + 1) + eaddr[1]]);
            half2v h2 = *reinterpret_cast<const half2v*>(&fkT[ROWB * (4 * q + 2) + eaddr[2]]);
            half2v h3 = *reinterpret_cast<const half2v*>(&fkT[ROWB * (4 * q + 3) + eaddr[3]]);
            o0 = fmaf(rv.x, (float)h0[0], o0); o1 = fmaf(rv.x, (float)h0[1], o1);
            o0 = fmaf(rv.y, (float)h1[0], o0); o1 = fmaf(rv.y, (float)h1[1], o1);
            o0 = fmaf(rv.z, (float)h2[0], o0); o1 = fmaf(rv.z, (float)h2[1], o1);
            o0 = fmaf(rv.w, (float)h3[0], o0); o1 = fmaf(rv.w, (float)h3[1], o1);
        }
        f32x2 ov; ov[0] = o0 + bv.x; ov[1] = o1 + bv.y;
        __builtin_nontemporal_store(
            ov, reinterpret_cast<f32x2*>(out + (size_t)nd * DIM + d0));

        if (!hn) break;
        // rotate pipeline registers
        nd  = ndn;
        mkc = mk_n;
        wc  = mk_n ? 0.0f : tw_n;
#pragma unroll
        for (int i = 0; i < 8; ++i) gb[i] = gb_n[i];
    }
}

extern "C" void kernel_launch(void* const* d_in, const int* in_sizes, int n_in,
                              void* d_out, int out_size, void* d_ws, size_t ws_size,
                              hipStream_t stream) {
    const float* feat = (const float*)d_in[0];
    const float* W    = (const float*)d_in[1];
    const float* bias = (const float*)d_in[2];
    const float* tkw  = (const float*)d_in[3];
    const int*   idx  = (const int*)d_in[4];
    float* out = (float*)d_out;

    const int n = in_sizes[0] / DIM;                       // 50000
    _Float16* hq = (_Float16*)d_ws;                        // n*128*2 = 12.8 MB

    const int sblocks = (n + 3) / 4;                       // 12500 (softk, 1 wave)

    gemm128<<<GEMM_BLOCKS, 256, 0, stream>>>(feat, W, hq, n);
    softk<<<sblocks, 64, 0, stream>>>(hq, bias, tkw, idx, out, n);
}